// Round 9
// baseline (9974.213 us; speedup 1.0000x reference)
//
#include <hip/hip_runtime.h>

// 2-layer tanh RNN, B=64 T=512 H=512, f32 in/out.
// R9 design: SELF-VALIDATING TAGGED DATA, no barriers/flags in the loop.
// h elements are u32 = (bf16 value)<<16 | step_tag(low16). Consumers poll
// the data itself until all tags match the expected step; producers' stores
// ARE the publish. Waves run free (disjoint batch cols); one syncthreads
// total (LDS weight staging). Ring WAR safety by dependency order:
//  - within a layer, peer overwrite happens-after my reads (peer needed my
//    previous write to advance);
//  - layer-0 throttled by a 1-elem tag probe of h2[t-2] => lead<=3 < D1=4;
//  - layer-1 can never lead layer-0 (needs h1[t+1]).
// Weights: Whh = hi(bf16, regs) + lo(bf16, LDS), 2 MFMA passes (f32-grade);
// Wih1 = hi only (LDS). xw1 fused as concat-K; layer-1 does h2-part MFMAs
// while h1[t+1] is still in flight, then polls h1.
// History: R4-R8 all ~9-11us/step -- the store->drain->flag->poll->load
// skeleton serializes ~4 coherent-point RTs/step regardless of flavor.

#define HD 512
#define BATCH 64
#define SEQ 512
#define NVOCAB 25
#define OUTD 1000
#define NWG 32
#define BH (BATCH * HD)   // elements per h slice
#define TAGMASK 0x0000FFFF0000FFFFULL

typedef unsigned short u16;
typedef unsigned int u32;
typedef unsigned long long u64;
typedef __attribute__((ext_vector_type(8))) short short8;  // 8 bf16
typedef __attribute__((ext_vector_type(4))) float f32x4;

union FragU { u16 h[8]; u32 w[4]; u64 q[2]; short8 v; };

__device__ __forceinline__ float bf2f(u16 v) {
    union { u32 u; float f; } c; c.u = ((u32)v) << 16; return c.f;
}
__device__ __forceinline__ u16 f2bf(float f) {
    union { float f; u32 u; } c; c.f = f;
    return (u16)((c.u + 0x7FFFu + ((c.u >> 16) & 1u)) >> 16);  // RNE
}
__device__ __forceinline__ u64 al64(const u64* p) {
    return __hip_atomic_load(p, __ATOMIC_RELAXED, __HIP_MEMORY_SCOPE_AGENT);
}
__device__ __forceinline__ u32 al32(const u32* p) {
    return __hip_atomic_load(p, __ATOMIC_RELAXED, __HIP_MEMORY_SCOPE_AGENT);
}
__device__ __forceinline__ void as64(u64* p, u64 v) {
    __hip_atomic_store(p, v, __ATOMIC_RELAXED, __HIP_MEMORY_SCOPE_AGENT);
}

// Zero header+rings (tag 0 everywhere; h1[0]/h2[0] = value 0 tag 0 = valid).
// Thread 1024 probes x's int width (int64 => odd int32 words all 0).
__global__ void init_kernel(u32* p, int n, const int* x32, int* flag) {
    int i = blockIdx.x * 256 + threadIdx.x;
    if (i == 1024) {
        int all0 = 1;
        for (int j = 0; j < 64; ++j) if (x32[2 * j + 1] != 0) all0 = 0;
        *flag = all0;
    } else if (i < n) p[i] = 0u;
}

__global__ __launch_bounds__(256, 1) void rnn_fused(
    const float* __restrict__ Whh0, const float* __restrict__ Wih0,
    const int* __restrict__ x,
    const float* __restrict__ bih0, const float* __restrict__ bhh0,
    const float* __restrict__ Whh1, const float* __restrict__ Wih1,
    const float* __restrict__ bih1, const float* __restrict__ bhh1,
    u32* h1ring, u32* h2ring, float* h2final, int* hdr)
{
    const int tid  = threadIdx.x;
    const int wave = tid >> 6;
    const int lane = tid & 63;
    const int quad = lane >> 4;
    const int l16  = lane & 15;
    const int layer = blockIdx.x >> 5;          // 0 or 1
    const int rowbase = (blockIdx.x & 31) * 16; // 32 WGs x 16 rows = 512
    const int arow = rowbase + l16;             // A row (m = lane&15)
    const int row0 = rowbase + quad * 4;        // C/D rows: quad*4 + reg
    const int col  = wave * 16 + l16;           // C/D col (batch)

    // lds[0] = Whh-lo frags; lds[1] = Wih1-hi frags (layer 1 only). 32 KB.
    __shared__ u16 lds[2][16][4][16][8];

    const float* Wself = layer ? Whh1 : Whh0;
    short8 Ah[16];                              // Whh-hi, register-resident
    #pragma unroll
    for (int kc = 0; kc < 16; ++kc) {
        FragU th, tl;
        #pragma unroll
        for (int j = 0; j < 8; ++j) {
            float w = Wself[arow * HD + kc * 32 + quad * 8 + j];
            u16 hi = f2bf(w);
            th.h[j] = hi;
            tl.h[j] = f2bf(w - bf2f(hi));
        }
        Ah[kc] = th.v;
        if (wave == 0) *(short8*)&lds[0][kc][quad][l16][0] = tl.v;
    }
    if (layer && wave == 1) {
        #pragma unroll
        for (int kc = 0; kc < 16; ++kc) {
            FragU th;
            #pragma unroll
            for (int j = 0; j < 8; ++j)
                th.h[j] = f2bf(Wih1[arow * HD + kc * 32 + quad * 8 + j]);
            *(short8*)&lds[1][kc][quad][l16][0] = th.v;
        }
    }
    const float* bA = layer ? bih1 : bih0;
    const float* bB = layer ? bhh1 : bhh0;
    float bsum[4];
    #pragma unroll
    for (int i = 0; i < 4; ++i) bsum[i] = bA[row0 + i] + bB[row0 + i];
    const int is64 = hdr[1024];
    __syncthreads();   // the ONLY barrier: LDS weights ready

    if (layer == 0) {
        for (int t = 0; t < SEQ; ++t) {
            int xi = is64 ? (int)((const long long*)x)[col * SEQ + t]
                          : x[col * SEQ + t];
            float xw[4];
            #pragma unroll
            for (int i = 0; i < 4; ++i) xw[i] = Wih0[(row0 + i) * NVOCAB + xi];

            // poll h1[t] (own 16 cols) for tag t; throttle on h2 tag >= t-2
            const u64* hp = (const u64*)(h1ring + (size_t)(t & 3) * BH + col * HD);
            const u32* thp = h2ring + (size_t)((t - 2) & 1) * BH + col * HD;
            const u64 rep = ((u64)(u32)t) | (((u64)(u32)t) << 32);
            u64 B[64]; u64 bad; long g = 0;
            do {
                bad = 0;
                #pragma unroll
                for (int kc = 0; kc < 16; ++kc)
                    #pragma unroll
                    for (int m = 0; m < 4; ++m) {
                        u64 q = al64(hp + kc * 16 + quad * 4 + m);
                        B[kc * 4 + m] = q;
                        bad |= (q ^ rep) & TAGMASK;
                    }
                if (t >= 3) {
                    u32 th = al32(thp);
                    if ((int)(th & 0xFFFFu) < t - 2) bad |= 1;
                }
            } while (__ballot(bad != 0ULL) != 0ULL && ++g < (1L << 18));

            f32x4 acc0 = {0.f,0.f,0.f,0.f}, acc1 = {0.f,0.f,0.f,0.f};
            #pragma unroll
            for (int kc = 0; kc < 16; ++kc) {
                FragU fb;
                #pragma unroll
                for (int m = 0; m < 4; ++m) {
                    u64 q = B[kc * 4 + m];
                    fb.w[m] = (u32)((q >> 16) & 0xFFFFu) | ((u32)(q >> 48) << 16);
                }
                acc0 = __builtin_amdgcn_mfma_f32_16x16x32_bf16(Ah[kc], fb.v, acc0, 0, 0, 0);
                short8 lo = *(short8*)&lds[0][kc][quad][l16][0];
                acc1 = __builtin_amdgcn_mfma_f32_16x16x32_bf16(lo, fb.v, acc1, 0, 0, 0);
            }
            u32 ev[4];
            const u32 tagw = (u32)(t + 1) & 0xFFFFu;
            #pragma unroll
            for (int i = 0; i < 4; ++i) {
                float hf = tanhf(acc0[i] + acc1[i] + bsum[i] + xw[i]);
                ev[i] = ((u32)f2bf(hf) << 16) | tagw;
            }
            u64* dst = (u64*)(h1ring + (size_t)((t + 1) & 3) * BH + col * HD + row0);
            as64(dst + 0, (u64)ev[0] | ((u64)ev[1] << 32));
            as64(dst + 1, (u64)ev[2] | ((u64)ev[3] << 32));
        }
    } else {
        for (int t = 0; t < SEQ; ++t) {
            // ---- phase A: poll h2[t] (tag t), run Whh1 hi+lo MFMAs ----
            const u64* hp = (const u64*)(h2ring + (size_t)(t & 1) * BH + col * HD);
            u64 rep = ((u64)(u32)t) | (((u64)(u32)t) << 32);
            u64 B[64]; u64 bad; long g = 0;
            do {
                bad = 0;
                #pragma unroll
                for (int kc = 0; kc < 16; ++kc)
                    #pragma unroll
                    for (int m = 0; m < 4; ++m) {
                        u64 q = al64(hp + kc * 16 + quad * 4 + m);
                        B[kc * 4 + m] = q;
                        bad |= (q ^ rep) & TAGMASK;
                    }
            } while (__ballot(bad != 0ULL) != 0ULL && ++g < (1L << 18));

            f32x4 acc0 = {0.f,0.f,0.f,0.f}, acc1 = {0.f,0.f,0.f,0.f};
            #pragma unroll
            for (int kc = 0; kc < 16; ++kc) {
                FragU fb;
                #pragma unroll
                for (int m = 0; m < 4; ++m) {
                    u64 q = B[kc * 4 + m];
                    fb.w[m] = (u32)((q >> 16) & 0xFFFFu) | ((u32)(q >> 48) << 16);
                }
                acc0 = __builtin_amdgcn_mfma_f32_16x16x32_bf16(Ah[kc], fb.v, acc0, 0, 0, 0);
                short8 lo = *(short8*)&lds[0][kc][quad][l16][0];
                acc1 = __builtin_amdgcn_mfma_f32_16x16x32_bf16(lo, fb.v, acc1, 0, 0, 0);
            }

            // ---- phase B: poll h1[t+1] (tag t+1), run Wih1-hi MFMAs ----
            const u64* hq = (const u64*)(h1ring + (size_t)((t + 1) & 3) * BH + col * HD);
            rep = ((u64)(u32)(t + 1)) | (((u64)(u32)(t + 1)) << 32);
            g = 0;
            do {
                bad = 0;
                #pragma unroll
                for (int kc = 0; kc < 16; ++kc)
                    #pragma unroll
                    for (int m = 0; m < 4; ++m) {
                        u64 q = al64(hq + kc * 16 + quad * 4 + m);
                        B[kc * 4 + m] = q;
                        bad |= (q ^ rep) & TAGMASK;
                    }
            } while (__ballot(bad != 0ULL) != 0ULL && ++g < (1L << 18));

            #pragma unroll
            for (int kc = 0; kc < 16; ++kc) {
                FragU fb;
                #pragma unroll
                for (int m = 0; m < 4; ++m) {
                    u64 q = B[kc * 4 + m];
                    fb.w[m] = (u32)((q >> 16) & 0xFFFFu) | ((u32)(q >> 48) << 16);
                }
                short8 wih = *(short8*)&lds[1][kc][quad][l16][0];
                acc0 = __builtin_amdgcn_mfma_f32_16x16x32_bf16(wih, fb.v, acc0, 0, 0, 0);
            }

            // ---- epilogue ----
            if (t < SEQ - 1) {
                u32 ev[4];
                const u32 tagw = (u32)(t + 1) & 0xFFFFu;
                #pragma unroll
                for (int i = 0; i < 4; ++i) {
                    float hf = tanhf(acc0[i] + acc1[i] + bsum[i]);
                    ev[i] = ((u32)f2bf(hf) << 16) | tagw;
                }
                u64* dst = (u64*)(h2ring + (size_t)((t + 1) & 1) * BH + col * HD + row0);
                as64(dst + 0, (u64)ev[0] | ((u64)ev[1] << 32));
                as64(dst + 1, (u64)ev[2] | ((u64)ev[3] << 32));
            } else {
                float hf[4];
                #pragma unroll
                for (int i = 0; i < 4; ++i)
                    hf[i] = tanhf(acc0[i] + acc1[i] + bsum[i]);
                *(f32x4*)(h2final + col * HD + row0) = *(f32x4*)hf;
            }
        }
    }
}

__global__ __launch_bounds__(256) void out_kernel(
    const float* __restrict__ h2last, const float* __restrict__ Wout,
    const float* __restrict__ bout, float* __restrict__ out)
{
    int o = blockIdx.x * 256 + threadIdx.x;
    int b = blockIdx.y;
    if (o >= OUTD) return;
    const float* hrow = h2last + b * HD;
    const float* wrow = Wout + o * HD;
    float acc = 0.f;
    for (int k = 0; k < HD; k += 4) {
        float4 hv = *(const float4*)(hrow + k);
        float4 wv = *(const float4*)(wrow + k);
        acc += hv.x * wv.x + hv.y * wv.y + hv.z * wv.z + hv.w * wv.w;
    }
    out[b * OUTD + o] = acc + bout[o];
}

extern "C" void kernel_launch(void* const* d_in, const int* in_sizes, int n_in,
                              void* d_out, int out_size, void* d_ws, size_t ws_size,
                              hipStream_t stream) {
    const int*   x     = (const int*)d_in[0];
    const float* W_ih0 = (const float*)d_in[1];
    const float* W_hh0 = (const float*)d_in[2];
    const float* b_ih0 = (const float*)d_in[3];
    const float* b_hh0 = (const float*)d_in[4];
    const float* W_ih1 = (const float*)d_in[5];
    const float* W_hh1 = (const float*)d_in[6];
    const float* b_ih1 = (const float*)d_in[7];
    const float* b_hh1 = (const float*)d_in[8];
    const float* W_out = (const float*)d_in[9];
    const float* b_out = (const float*)d_in[10];

    // ws: hdr[2048] int (is64 @1024) | h1ring u32[4][BH] | h2ring u32[2][BH]
    //     | h2final f32[BH]   => 8K + 512K + 256K + 128K = 904 KB
    const size_t needed = 8192 + (size_t)4 * BH * 4 + (size_t)2 * BH * 4
                        + (size_t)BH * 4;
    if (ws_size < needed) return;  // signature: absmax=0.149 non-NaN => ws short

    int* hdr = (int*)d_ws;
    u32* h1ring = (u32*)((char*)d_ws + 8192);
    u32* h2ring = h1ring + (size_t)4 * BH;
    float* h2final = (float*)(h2ring + (size_t)2 * BH);

    const int nzero = (int)((8192 + (size_t)6 * BH * 4) / 4);  // hdr + rings
    init_kernel<<<(nzero + 255) / 256, 256, 0, stream>>>((u32*)d_ws, nzero, x, hdr + 1024);
    rnn_fused<<<2 * NWG, 256, 0, stream>>>(W_hh0, W_ih0, x, b_ih0, b_hh0,
                                           W_hh1, W_ih1, b_ih1, b_hh1,
                                           h1ring, h2ring, h2final, hdr);
    out_kernel<<<dim3(4, BATCH), 256, 0, stream>>>(h2final, W_out, b_out, (float*)d_out);
}

// Round 10
// 4764.743 us; speedup vs baseline: 2.0933x; 2.0933x over previous
//
#include <hip/hip_runtime.h>

// 2-layer tanh RNN, B=64 T=512 H=512, f32 in/out.
// Weights split hi+lo bf16 (w=hi+lo) -> 2 MFMA passes/operand, f32-grade acc.
// 64 WGs x 256 thr; blocks 0..31 layer 0, 32..63 layer 1 (xw1 fused concat-K,
// one step behind L0). h rings bf16; cross-WG data = agent-scope relaxed
// atomics; per-WG padded flags, RELEASE publish after vmcnt-drain barrier.
// R10: (a) h1 ring depth 8 / h2 depth 4 -- R7's 2-slot rings forced L0<->L1
// LOCKSTEP (L0 step t waited flags1>=t-1), making the period TWO ~4.4us
// handoffs = 8.9us/step. Deep rings give L0 ~6 steps of WAR slack -> period
// = one handoff. (b) s_sleep(1) poll backoff: R9 proved poll traffic queues
// at the MALL ahead of critical-path ops (FETCH 266->725MB, handoff 4.4->9.7us).
// (c) L1 phase-split: h2-half MFMAs run while h1[t+1] is still being made.

#define HD 512
#define BATCH 64
#define SEQ 512
#define NVOCAB 25
#define OUTD 1000
#define NWG 32
#define BH (BATCH * HD)
#define D1 8    // h1 ring depth
#define D2 4    // h2 ring depth
#define FPAD 16 // ints per flag slot (64 B line)

typedef unsigned short u16;
typedef unsigned int u32;
typedef unsigned long long u64;
typedef __attribute__((ext_vector_type(8))) short short8;  // 8 bf16
typedef __attribute__((ext_vector_type(4))) float f32x4;

union FragU { u16 h[8]; u64 q[2]; short8 v; };

__device__ __forceinline__ float bf2f(u16 v) {
    union { u32 u; float f; } c; c.u = ((u32)v) << 16; return c.f;
}
__device__ __forceinline__ u16 f2bf(float f) {
    union { float f; u32 u; } c; c.f = f;
    return (u16)((c.u + 0x7FFFu + ((c.u >> 16) & 1u)) >> 16);  // RNE
}
__device__ __forceinline__ short8 ld_frag(const u16* p) {
    FragU f; u64* q = (u64*)p;
    f.q[0] = __hip_atomic_load(q + 0, __ATOMIC_RELAXED, __HIP_MEMORY_SCOPE_AGENT);
    f.q[1] = __hip_atomic_load(q + 1, __ATOMIC_RELAXED, __HIP_MEMORY_SCOPE_AGENT);
    return f.v;
}

// Zero header+rings; thread 1024 probes x's int width (int64 => odd words 0).
__global__ void init_kernel(u32* p, int n, const int* x32, int* flag) {
    int i = blockIdx.x * 256 + threadIdx.x;
    if (i == 1024) {
        int all0 = 1;
        for (int j = 0; j < 64; ++j) if (x32[2 * j + 1] != 0) all0 = 0;
        *flag = all0;
    } else if (i < n) p[i] = 0u;
}

// hdr (ints): flags0[32*FPAD] @0 | flags1[32*FPAD] @512 | is64 @1024
__global__ __launch_bounds__(256, 1) void rnn_fused(
    const float* __restrict__ Whh0, const float* __restrict__ Wih0,
    const int* __restrict__ x,
    const float* __restrict__ bih0, const float* __restrict__ bhh0,
    const float* __restrict__ Whh1, const float* __restrict__ Wih1,
    const float* __restrict__ bih1, const float* __restrict__ bhh1,
    u16* h1ring, u16* h2ring, float* h2final, int* hdr)
{
    int* flags0 = hdr;             // flags0[g*FPAD] == v <=> L0 WG g finished step v-1
    int* flags1 = hdr + NWG * FPAD;
    const int tid  = threadIdx.x;
    const int wave = tid >> 6;
    const int lane = tid & 63;
    const int quad = lane >> 4;
    const int l16  = lane & 15;
    const int layer = blockIdx.x >> 5;          // 0 or 1
    const int rowbase = (blockIdx.x & 31) * 16; // 32 WGs x 16 rows = 512
    const int arow = rowbase + l16;             // A row (m = lane&15)
    const int row0 = rowbase + quad * 4;        // C/D rows: quad*4 + reg
    const int col  = wave * 16 + l16;           // C/D col (batch)
    int* myflag = (layer ? flags1 : flags0) + (blockIdx.x & 31) * FPAD;

    __shared__ u16 ldsW[2][16][4][16][8];       // Wih1 hi/lo frags, 32 KB

    // Whh split hi/lo bf16, register-resident: A[m=lane&15][k=quad*8+j].
    const float* Wself = layer ? Whh1 : Whh0;
    short8 Ah[16], Al[16];
    #pragma unroll
    for (int kc = 0; kc < 16; ++kc) {
        FragU th, tl;
        #pragma unroll
        for (int j = 0; j < 8; ++j) {
            float w = Wself[arow * HD + kc * 32 + quad * 8 + j];
            u16 hi = f2bf(w);
            th.h[j] = hi;
            tl.h[j] = f2bf(w - bf2f(hi));
        }
        Ah[kc] = th.v; Al[kc] = tl.v;
    }
    if (layer && wave == 0) {  // all 4 waves share the same A rows
        #pragma unroll
        for (int kc = 0; kc < 16; ++kc) {
            FragU th, tl;
            #pragma unroll
            for (int j = 0; j < 8; ++j) {
                float w = Wih1[arow * HD + kc * 32 + quad * 8 + j];
                u16 hi = f2bf(w);
                th.h[j] = hi;
                tl.h[j] = f2bf(w - bf2f(hi));
            }
            *(short8*)&ldsW[0][kc][quad][l16][0] = th.v;
            *(short8*)&ldsW[1][kc][quad][l16][0] = tl.v;
        }
    }
    const float* bA = layer ? bih1 : bih0;
    const float* bB = layer ? bhh1 : bhh0;
    float bsum[4];
    #pragma unroll
    for (int i = 0; i < 4; ++i) bsum[i] = bA[row0 + i] + bB[row0 + i];
    const int is64 = hdr[1024];
    __syncthreads();

    if (layer == 0) {
        for (int t = 0; t < SEQ; ++t) {
            // x gather is h-independent: issue before the wait
            int xi = is64 ? (int)((const long long*)x)[col * SEQ + t]
                          : x[col * SEQ + t];
            float xw[4];
            #pragma unroll
            for (int i = 0; i < 4; ++i) xw[i] = Wih0[(row0 + i) * NVOCAB + xi];

            // wait: peers flags0 >= t (h1[t] done); WAR flags1 >= t-7
            // (L1 readers of slot (t+1)&7 retired; ~6 steps of slack).
            if (wave == 0) {
                const int g = lane & 31;
                int* p = (lane < 32 ? flags0 : flags1) + g * FPAD;
                const int tgt = (lane < 32) ? t : (t - (D1 - 1));
                long guard = 0;
                while (true) {
                    int v = __hip_atomic_load(p, __ATOMIC_RELAXED,
                                              __HIP_MEMORY_SCOPE_AGENT);
                    if (__ballot(v < tgt) == 0ULL) break;
                    __builtin_amdgcn_s_sleep(1);
                    if (++guard > (1L << 21)) break;
                }
            }
            __syncthreads();

            const u16* hp = h1ring + (size_t)(t & (D1 - 1)) * BH + col * HD;
            short8 B2[16];
            #pragma unroll
            for (int kc = 0; kc < 16; ++kc)
                B2[kc] = ld_frag(hp + kc * 32 + quad * 8);
            f32x4 acc0 = {0.f,0.f,0.f,0.f}, acc1 = {0.f,0.f,0.f,0.f};
            #pragma unroll
            for (int kc = 0; kc < 16; ++kc) {
                acc0 = __builtin_amdgcn_mfma_f32_16x16x32_bf16(Ah[kc], B2[kc], acc0, 0, 0, 0);
                acc1 = __builtin_amdgcn_mfma_f32_16x16x32_bf16(Al[kc], B2[kc], acc1, 0, 0, 0);
            }
            u16 hv[4];
            #pragma unroll
            for (int i = 0; i < 4; ++i)
                hv[i] = f2bf(tanhf(acc0[i] + acc1[i] + bsum[i] + xw[i]));
            u64 pk = (u64)hv[0] | ((u64)hv[1] << 16) | ((u64)hv[2] << 32) | ((u64)hv[3] << 48);
            u64* dst = (u64*)(h1ring + (size_t)((t + 1) & (D1 - 1)) * BH + col * HD + row0);
            __hip_atomic_store(dst, pk, __ATOMIC_RELAXED, __HIP_MEMORY_SCOPE_AGENT);

            __syncthreads();  // drains vmcnt: h1[t+1] at coherent point
            if (tid == 0)
                __hip_atomic_store(myflag, t + 1, __ATOMIC_RELEASE,
                                   __HIP_MEMORY_SCOPE_AGENT);
        }
    } else {
        for (int t = 0; t < SEQ; ++t) {
            // ---- phase A: wait peers flags1 >= t (h2[t]; self-paced, fast) ----
            if (wave == 0) {
                const int g = lane & 31;
                int* p = flags1 + g * FPAD;
                long guard = 0;
                while (true) {
                    int v = __hip_atomic_load(p, __ATOMIC_RELAXED,
                                              __HIP_MEMORY_SCOPE_AGENT);
                    if (__ballot(v < t) == 0ULL) break;
                    __builtin_amdgcn_s_sleep(1);
                    if (++guard > (1L << 21)) break;
                }
            }
            __syncthreads();
            const u16* hp = h2ring + (size_t)(t & (D2 - 1)) * BH + col * HD;
            short8 B2[16];
            #pragma unroll
            for (int kc = 0; kc < 16; ++kc)
                B2[kc] = ld_frag(hp + kc * 32 + quad * 8);
            f32x4 acc0 = {0.f,0.f,0.f,0.f}, acc1 = {0.f,0.f,0.f,0.f};
            #pragma unroll
            for (int kc = 0; kc < 16; ++kc) {
                acc0 = __builtin_amdgcn_mfma_f32_16x16x32_bf16(Ah[kc], B2[kc], acc0, 0, 0, 0);
                acc1 = __builtin_amdgcn_mfma_f32_16x16x32_bf16(Al[kc], B2[kc], acc1, 0, 0, 0);
            }

            // ---- phase B: wait flags0 >= t+1 (h1[t+1]), then Wih1 MFMAs ----
            if (wave == 0) {
                const int g = lane & 31;
                int* p = flags0 + g * FPAD;
                const int tgt = t + 1;
                long guard = 0;
                while (true) {
                    int v = __hip_atomic_load(p, __ATOMIC_RELAXED,
                                              __HIP_MEMORY_SCOPE_AGENT);
                    if (__ballot(v < tgt) == 0ULL) break;
                    __builtin_amdgcn_s_sleep(1);
                    if (++guard > (1L << 21)) break;
                }
            }
            __syncthreads();
            const u16* hq = h1ring + (size_t)((t + 1) & (D1 - 1)) * BH + col * HD;
            short8 B1[16];
            #pragma unroll
            for (int kc = 0; kc < 16; ++kc)
                B1[kc] = ld_frag(hq + kc * 32 + quad * 8);
            #pragma unroll
            for (int kc = 0; kc < 16; ++kc) {
                short8 w1h = *(short8*)&ldsW[0][kc][quad][l16][0];
                short8 w1l = *(short8*)&ldsW[1][kc][quad][l16][0];
                acc0 = __builtin_amdgcn_mfma_f32_16x16x32_bf16(w1h, B1[kc], acc0, 0, 0, 0);
                acc1 = __builtin_amdgcn_mfma_f32_16x16x32_bf16(w1l, B1[kc], acc1, 0, 0, 0);
            }

            // ---- epilogue ----
            if (t < SEQ - 1) {
                u16 hv[4];
                #pragma unroll
                for (int i = 0; i < 4; ++i)
                    hv[i] = f2bf(tanhf(acc0[i] + acc1[i] + bsum[i]));
                u64 pk = (u64)hv[0] | ((u64)hv[1] << 16) | ((u64)hv[2] << 32) | ((u64)hv[3] << 48);
                u64* dst = (u64*)(h2ring + (size_t)((t + 1) & (D2 - 1)) * BH + col * HD + row0);
                __hip_atomic_store(dst, pk, __ATOMIC_RELAXED, __HIP_MEMORY_SCOPE_AGENT);
            } else {
                float hf[4];
                #pragma unroll
                for (int i = 0; i < 4; ++i)
                    hf[i] = tanhf(acc0[i] + acc1[i] + bsum[i]);
                *(f32x4*)(h2final + col * HD + row0) = *(f32x4*)hf;  // exact final h2
            }
            __syncthreads();  // drains vmcnt
            if (tid == 0)
                __hip_atomic_store(myflag, t + 1, __ATOMIC_RELEASE,
                                   __HIP_MEMORY_SCOPE_AGENT);
        }
    }
}

__global__ __launch_bounds__(256) void out_kernel(
    const float* __restrict__ h2last, const float* __restrict__ Wout,
    const float* __restrict__ bout, float* __restrict__ out)
{
    int o = blockIdx.x * 256 + threadIdx.x;
    int b = blockIdx.y;
    if (o >= OUTD) return;
    const float* hrow = h2last + b * HD;
    const float* wrow = Wout + o * HD;
    float acc = 0.f;
    for (int k = 0; k < HD; k += 4) {
        float4 hv = *(const float4*)(hrow + k);
        float4 wv = *(const float4*)(wrow + k);
        acc += hv.x * wv.x + hv.y * wv.y + hv.z * wv.z + hv.w * wv.w;
    }
    out[b * OUTD + o] = acc + bout[o];
}

extern "C" void kernel_launch(void* const* d_in, const int* in_sizes, int n_in,
                              void* d_out, int out_size, void* d_ws, size_t ws_size,
                              hipStream_t stream) {
    const int*   x     = (const int*)d_in[0];
    const float* W_ih0 = (const float*)d_in[1];
    const float* W_hh0 = (const float*)d_in[2];
    const float* b_ih0 = (const float*)d_in[3];
    const float* b_hh0 = (const float*)d_in[4];
    const float* W_ih1 = (const float*)d_in[5];
    const float* W_hh1 = (const float*)d_in[6];
    const float* b_ih1 = (const float*)d_in[7];
    const float* b_hh1 = (const float*)d_in[8];
    const float* W_out = (const float*)d_in[9];
    const float* b_out = (const float*)d_in[10];

    // ws: hdr[2048] int | h1ring u16[D1][BH] (512K) | h2ring u16[D2][BH] (256K)
    //     | h2final f32[BH] (128K)  => 904 KB total (R9's size passed)
    const size_t needed = 8192 + (size_t)D1 * BH * 2 + (size_t)D2 * BH * 2
                        + (size_t)BH * 4;
    if (ws_size < needed) return;  // signature: absmax=0.149 non-NaN => ws short

    int* hdr = (int*)d_ws;
    u16* h1ring = (u16*)((char*)d_ws + 8192);
    u16* h2ring = h1ring + (size_t)D1 * BH;
    float* h2final = (float*)(h2ring + (size_t)D2 * BH);

    const int nzero = (int)((8192 + (size_t)(D1 + D2) * BH * 2) / 4);
    init_kernel<<<(nzero + 255) / 256, 256, 0, stream>>>((u32*)d_ws, nzero, x, hdr + 1024);
    rnn_fused<<<2 * NWG, 256, 0, stream>>>(W_hh0, W_ih0, x, b_ih0, b_hh0,
                                           W_hh1, W_ih1, b_ih1, b_hh1,
                                           h1ring, h2ring, h2final, hdr);
    out_kernel<<<dim3(4, BATCH), 256, 0, stream>>>(h2final, W_out, b_out, (float*)d_out);
}